// Round 3
// baseline (2634.133 us; speedup 1.0000x reference)
//
#include <hip/hip_runtime.h>
#include <math.h>

// Archetipes RNN scan: T=256 sequential steps, M=16 modules, H=256, I=128.
// R10: clock-paced optimistic staging + tag validation; beacon = fallback.
// R9 post-mortem: 7.0 us/step, VALU ~1.0 us. Two findings:
//  (a) SQ_LDS_BANK_CONFLICT 5x up: staging writes dst[(tid&15)*256+(tid>>4)]
//      are 16-way bank conflicts (256 % 32 == 0) ~0.8 us/step serialized.
//  (b) Remaining ~5 us/step = serialized control chain (publish -> agg
//      poll-detect -> beacon RT -> consumer poll-detect -> stage RT).
// Changes:
//  1. LDS rows padded to HP=260 floats (1040 B, 16B-aligned): staging
//     store bank = (4*(lane&15)+(lane>>4))&31 -> 2-way (free per m136);
//     compute ds_read_b128 stays consecutive-16B conflict-free.
//  2. Fast path: per-block running deadline dl += S (s_memrealtime ticks).
//     At deadline, stage directly from g_hy and VALIDATE embedded tags
//     (thread checks its 4 packets; block-wide AND via LDS fail flag).
//     Fresh -> proceed with ZERO control hops. Stale -> fall back to the
//     proven R9 beacon poll, restage, adapt S += 96 and rebase dl = now;
//     on success S -= 1 (floor 96, cap 1024). Self-calibrating: converges
//     to the true step time regardless of RTC rate; worst case degrades
//     to ~R9 speed, never deadlocks (beacons still published every step).
//  3. Aggregator duty stays BEFORE the deadline (R9 placement): an agg
//     block that itself falls back must not wait on its own beacon.
// Correctness never depends on timing: tags gate data use; arithmetic
// order unchanged -> bitwise-stable outputs across graph replays.
// Weights register-resident (R3), conn-sparsity olist (R4), LDS
// out-buffering + single flush (R7), tagged packets + beacon (R9) kept.

#define DT_C    0.042f
#define GAMMA_C 2.7f
#define EPS_C   4.7f

constexpr int M = 16, H = 256, I = 128, T = 256;
constexpr int HP = H + 4;     // padded LDS row stride (16B-aligned, 2-way banks)
constexpr int NROW = M * H;   // 4096 packets per slot
constexpr int NBLK = 256;
constexpr int NTHR = 1024;    // 16 waves
constexpr int NAGG = 16;      // aggregator waves (wave 0 of blocks 0..15)
constexpr int NREP = 16;      // beacon replica lines

// deadline pacing (ticks of s_memrealtime; self-calibrating)
constexpr unsigned int S_INIT = 128, S_MIN = 96, S_MAX = 1024;
constexpr unsigned int S_UP = 96, S_DOWN = 1;

typedef float f32x4 __attribute__((ext_vector_type(4)));
typedef unsigned long long u64;
typedef unsigned int u32;

// Slot s (s=0..T) = hy after s steps. Packet = (tag<<32)|float_bits,
// tag = epoch + s + 1. Flat index p = h*16 + m.
__device__ __align__(64) u64 g_hy[(size_t)(T + 1) * NROW];   // 8.4 MB
__device__ __align__(64) u32 g_beacon[NREP][NAGG];           // 16 x 64 B
__device__ u32 g_epoch;

__global__ __launch_bounds__(NTHR) void rnn_persistent(
    const float* __restrict__ x,      // T*I
    const float* __restrict__ wm,     // M*M*H*H
    const float* __restrict__ conn,   // M*M
    const float* __restrict__ mask,   // M
    const float* __restrict__ W_in,   // M*H*I
    const float* __restrict__ W_rec,  // M*H*H
    const float* __restrict__ bias,   // M*H
    float* __restrict__ out)          // T*M*2*H state_seq, then T*M*H fb_seq
{
  const int h    = blockIdx.x;
  const int tid  = threadIdx.x;
  const int m    = tid >> 6;      // wave = module
  const int lane = tid & 63;

  __shared__ float hy_lds[2][M * HP];   // 2 x 16.25 KB, layout [m][h] padded
  __shared__ float outb_hz[T][M];       // 16 KB
  __shared__ float outb_fb[T][M];       // 16 KB
  __shared__ float s_c[M * M];
  __shared__ float s_scal[M];
  __shared__ int   s_olist[M][M];
  __shared__ float s_oc[M][M];
  __shared__ int   s_ocnt[M];
  __shared__ u32   s_base;
  __shared__ int   s_fail[2];

  if (tid == 0)
    s_base = __hip_atomic_load(&g_epoch, __ATOMIC_RELAXED, __HIP_MEMORY_SCOPE_AGENT);
  if (tid < 2) s_fail[tid] = 0;
  if (tid < M * M) s_c[tid] = conn[tid];
  __syncthreads();

  // ---- publish slot 0 = zeros ASAP (before heavy weight loads) ----
  const u32 base = s_base;
  if (tid < M) {
    const u64 pkt0 = ((u64)(base + 1u) << 32);   // hy = 0.0f, tag = base+1
    __hip_atomic_store(&g_hy[(size_t)h * M + tid], pkt0,
                       __ATOMIC_RELAXED, __HIP_MEMORY_SCOPE_AGENT);
  }

  if (tid < M) {
    float s = 0.f; int cnt = 0;
    for (int o = 0; o < M; ++o) {
      float c = s_c[tid * M + o];
      s += c;
      if (c != 0.f) { s_olist[tid][cnt] = o; s_oc[tid][cnt] = c; ++cnt; }
    }
    for (int k = cnt; k < M; ++k) { s_olist[tid][k] = 0; s_oc[tid][k] = 0.f; }
    s_ocnt[tid] = cnt;
    s_scal[tid] = 1.0f / fmaxf(s, 1.0f);
  }
  __syncthreads();

  const int   rowg  = m * H + h;    // global row (bias/W_rec/W_in)
  const float maskm = mask[m];
  const float biasv = bias[rowg];
  const float scal  = s_scal[m];
  const int   ocnt  = s_ocnt[m];

  // ---- one-time: weights into registers (conn pre-applied) ----
  f32x4 wreg[M];
#pragma unroll
  for (int k = 0; k < M; ++k) {
    if (k < ocnt) {
      const int o = s_olist[m][k];
      const f32x4 wv = *reinterpret_cast<const f32x4*>(
          wm + ((size_t)(m * M + o) * H + h) * H + 4 * lane);
      wreg[k] = wv * s_oc[m][k];
    } else {
      wreg[k] = (f32x4)0.f;
    }
  }
  const f32x4  wrec = *reinterpret_cast<const f32x4*>(W_rec + (size_t)rowg * H + 4 * lane);
  const float2 win  = *reinterpret_cast<const float2*>(W_in + (size_t)rowg * I + 2 * lane);

  float hz = 0.f;
  // x[0] prefetch (per-lane slice; same for every wave)
  float2 xd = *reinterpret_cast<const float2*>(x + 2 * lane);

  const bool is_agg = (h < NAGG) && (m == 0);   // wave 0 of blocks 0..15
  const int  mcol   = (tid & 15) * HP;          // staging LDS column base
  const int  hrow   = tid >> 4;                 // staging LDS row (0..63)
  int buf = 0;

  u32 S = S_INIT;
  long long dl = 0;

  for (int t = 0; t < T; ++t) {
    const u32 tgt = base + (u32)t + 1u;

    // ---- aggregator duty (every step; fallback liveness) ----
    if (is_agg) {
      const u64* wp = g_hy + (size_t)t * NROW + (size_t)h * 256 + lane;
      for (;;) {
        const u64 a0 = __hip_atomic_load(wp,       __ATOMIC_RELAXED, __HIP_MEMORY_SCOPE_AGENT);
        const u64 a1 = __hip_atomic_load(wp + 64,  __ATOMIC_RELAXED, __HIP_MEMORY_SCOPE_AGENT);
        const u64 a2 = __hip_atomic_load(wp + 128, __ATOMIC_RELAXED, __HIP_MEMORY_SCOPE_AGENT);
        const u64 a3 = __hip_atomic_load(wp + 192, __ATOMIC_RELAXED, __HIP_MEMORY_SCOPE_AGENT);
        const bool okw = (((u32)(a0 >> 32)) >= tgt) & (((u32)(a1 >> 32)) >= tgt) &
                         (((u32)(a2 >> 32)) >= tgt) & (((u32)(a3 >> 32)) >= tgt);
        if (__all(okw)) break;
        __builtin_amdgcn_s_sleep(1);
      }
      if (lane < NREP)
        __hip_atomic_store(&g_beacon[lane][h], tgt,
                           __ATOMIC_RELAXED, __HIP_MEMORY_SCOPE_AGENT);
      asm volatile("" ::: "memory");
    }

    // ---- fast path: wait block-local deadline, then stage + validate ----
    if (t > 0) {
      while ((long long)__builtin_amdgcn_s_memrealtime() < dl)
        __builtin_amdgcn_s_sleep(1);
    }
    asm volatile("" ::: "memory");

    bool ok;
    {
      const u64* src = g_hy + (size_t)t * NROW + tid;
      const u64 a0 = __hip_atomic_load(src,        __ATOMIC_RELAXED, __HIP_MEMORY_SCOPE_AGENT);
      const u64 a1 = __hip_atomic_load(src + 1024, __ATOMIC_RELAXED, __HIP_MEMORY_SCOPE_AGENT);
      const u64 a2 = __hip_atomic_load(src + 2048, __ATOMIC_RELAXED, __HIP_MEMORY_SCOPE_AGENT);
      const u64 a3 = __hip_atomic_load(src + 3072, __ATOMIC_RELAXED, __HIP_MEMORY_SCOPE_AGENT);
      ok = (((u32)(a0 >> 32)) >= tgt) & (((u32)(a1 >> 32)) >= tgt) &
           (((u32)(a2 >> 32)) >= tgt) & (((u32)(a3 >> 32)) >= tgt);
      float* dst = &hy_lds[buf][0];
      dst[mcol + hrow      ] = __uint_as_float((u32)a0);
      dst[mcol + hrow +  64] = __uint_as_float((u32)a1);
      dst[mcol + hrow + 128] = __uint_as_float((u32)a2);
      dst[mcol + hrow + 192] = __uint_as_float((u32)a3);
    }
    if (!ok) s_fail[buf] = 1;
    __syncthreads();   // bar1: LDS staged + fail flag visible; prev publish drained

    const bool fell = (s_fail[buf] != 0);
    if (fell) {
      // ---- fallback: proven R9 beacon poll, then restage (now fresh) ----
      const u32* bp = &g_beacon[(h + m) & (NREP - 1)][lane & 15];
      while (!__all(__hip_atomic_load(bp, __ATOMIC_RELAXED,
                                      __HIP_MEMORY_SCOPE_AGENT) >= tgt))
        __builtin_amdgcn_s_sleep(1);
      asm volatile("" ::: "memory");
      const u64* src = g_hy + (size_t)t * NROW + tid;
      const u64 a0 = __hip_atomic_load(src,        __ATOMIC_RELAXED, __HIP_MEMORY_SCOPE_AGENT);
      const u64 a1 = __hip_atomic_load(src + 1024, __ATOMIC_RELAXED, __HIP_MEMORY_SCOPE_AGENT);
      const u64 a2 = __hip_atomic_load(src + 2048, __ATOMIC_RELAXED, __HIP_MEMORY_SCOPE_AGENT);
      const u64 a3 = __hip_atomic_load(src + 3072, __ATOMIC_RELAXED, __HIP_MEMORY_SCOPE_AGENT);
      float* dst = &hy_lds[buf][0];
      dst[mcol + hrow      ] = __uint_as_float((u32)a0);
      dst[mcol + hrow +  64] = __uint_as_float((u32)a1);
      dst[mcol + hrow + 128] = __uint_as_float((u32)a2);
      dst[mcol + hrow + 192] = __uint_as_float((u32)a3);
      __syncthreads();   // bar2: fresh LDS visible
      if (tid == 0) s_fail[buf] = 0;   // visible by t+1's bar1, used at t+2
    }

    // ---- deadline bookkeeping (block-uniform decisions) ----
    if (t == 0) {
      dl = (long long)__builtin_amdgcn_s_memrealtime();
    } else if (fell) {
      S = (S + S_UP > S_MAX) ? S_MAX : S + S_UP;
      dl = (long long)__builtin_amdgcn_s_memrealtime();
    } else {
      S = (S > S_MIN + S_DOWN) ? S - S_DOWN : S_MIN;
      dl += (long long)S;
    }

    // input term (xd prefetched last iteration)
    float acc_o = win.x * (maskm * xd.x);
    acc_o = fmaf(win.y, maskm * xd.y, acc_o);
    // recurrent term
    {
      const f32x4 hp = *reinterpret_cast<const f32x4*>(&hy_lds[buf][m * HP + 4 * lane]);
      acc_o = fmaf(wrec.x, hp.x, acc_o);
      acc_o = fmaf(wrec.y, hp.y, acc_o);
      acc_o = fmaf(wrec.z, hp.z, acc_o);
      acc_o = fmaf(wrec.w, hp.w, acc_o);
    }
    // feedback: register weights x LDS hy fragments
    float acc_fb = 0.f;
#pragma unroll
    for (int k = 0; k < M; ++k) {
      if (k < ocnt) {
        const int o = s_olist[m][k];
        const f32x4 hp = *reinterpret_cast<const f32x4*>(&hy_lds[buf][o * HP + 4 * lane]);
        float po = wreg[k].x * hp.x;
        po = fmaf(wreg[k].y, hp.y, po);
        po = fmaf(wreg[k].z, hp.z, po);
        po = fmaf(wreg[k].w, hp.w, po);
        acc_fb += po;
      }
    }

    // wave-wide butterfly reduce
    for (int off = 32; off > 0; off >>= 1) {
      acc_fb += __shfl_xor(acc_fb, off);
      acc_o  += __shfl_xor(acc_o,  off);
    }

    if (lane == 0) {
      const float fb   = scal * acc_fb;
      const float hy_p = hy_lds[buf][m * HP + h];
      const float pre  = acc_o + biasv + fb;
      const float hz_n = hz + DT_C * (tanhf(pre) - GAMMA_C * hy_p - EPS_C * hz);
      const float hy_n = hy_p + DT_C * hz_n;
      hz = hz_n;
      // publish hy_t into slot t+1 (tag = tgt+1): the packet is the flag
      const u64 pkt = ((u64)(tgt + 1u) << 32) | (u64)__float_as_uint(hy_n);
      __hip_atomic_store(&g_hy[(size_t)(t + 1) * NROW + (size_t)h * M + m], pkt,
                         __ATOMIC_RELAXED, __HIP_MEMORY_SCOPE_AGENT);
      // buffer hz/fb in LDS; flushed once after the loop
      outb_hz[t][m] = hz_n;
      outb_fb[t][m] = fb;
    }

    if (t + 1 < T)
      xd = *reinterpret_cast<const float2*>(x + (size_t)(t + 1) * I + 2 * lane);
    buf ^= 1;
  }

  __syncthreads();   // outb_* visible; final publishes drained (vmcnt(0))

  // ---- one-time flush: hy from own g_hy slots, hz/fb from LDS ----
  const size_t fb_base = (size_t)T * M * 2 * H;
  for (int i = tid; i < T * M; i += NTHR) {
    const int t  = i >> 4;
    const int mm = i & 15;
    const u64 q = __hip_atomic_load(
        &g_hy[(size_t)(t + 1) * NROW + (size_t)h * M + mm],
        __ATOMIC_RELAXED, __HIP_MEMORY_SCOPE_AGENT);
    const float hyv = __uint_as_float((u32)q);
    const size_t so = (size_t)t * (M * 2 * H) + (size_t)mm * (2 * H);
    out[so + h]     = hyv;
    out[so + H + h] = outb_hz[t][mm];
    out[fb_base + (size_t)t * (M * H) + (size_t)mm * H + h] = outb_fb[t][mm];
  }

  // epoch bump for next launch/replay: strictly above every tag used here
  if (h == 0 && tid == 0)
    __hip_atomic_store(&g_epoch, base + (u32)(T + 2),
                       __ATOMIC_RELAXED, __HIP_MEMORY_SCOPE_AGENT);
}

extern "C" void kernel_launch(void* const* d_in, const int* in_sizes, int n_in,
                              void* d_out, int out_size, void* d_ws, size_t ws_size,
                              hipStream_t stream) {
  const float* x     = (const float*)d_in[0];
  const float* wm    = (const float*)d_in[1];
  const float* conn  = (const float*)d_in[2];
  const float* mask  = (const float*)d_in[3];
  const float* W_in  = (const float*)d_in[4];
  const float* W_rec = (const float*)d_in[5];
  const float* bias  = (const float*)d_in[6];

  rnn_persistent<<<NBLK, NTHR, 0, stream>>>(
      x, wm, conn, mask, W_in, W_rec, bias, (float*)d_out);
}